// Round 8
// baseline (449.268 us; speedup 1.0000x reference)
//
#include <hip/hip_runtime.h>
#include <math.h>

#define IN_FEATS 128
#define OUT_FEATS 64
#define NEG_SLOPE 0.2f
#define BSH 8                      // bucket = dst >> 8 (256 nodes/bucket)
#define BNODES (1 << BSH)
#define CHUNK 4096                 // edges per block in bucket passes
#define EPT 16                     // edges per thread (CHUNK/256)
#define EID_BITS 21                // n_edges < 2^21

// monotone float<->uint map for atomicMax on signed floats (0 == -inf floor)
__device__ __forceinline__ unsigned f2u_ord(float f) {
  unsigned b = __float_as_uint(f);
  return (b & 0x80000000u) ? ~b : (b | 0x80000000u);
}
__device__ __forceinline__ float u2f_ord(unsigned u) {
  return __uint_as_float((u & 0x80000000u) ? (u ^ 0x80000000u) : ~u);
}

// ---------------------------------------------------------------------------
// K1: h[n][o] = sum_k feat[n][k] * W[o][k]
// Lane-per-node: feat row in 128 VGPRs (deep vmcnt queue), W lane-uniform
// broadcast loads (1 line/instr, L1-hit), 4 independent accumulators.
// __launch_bounds__(128,2) -> 256-VGPR cap, no spill (R1 died on the 64 cap).
// ---------------------------------------------------------------------------
__global__ __launch_bounds__(128, 2)
void gemm_h_kernel(const float* __restrict__ feat,
                   const float* __restrict__ W,
                   float* __restrict__ h, int n_nodes) {
  const int n = blockIdx.x * blockDim.x + threadIdx.x;
  if (n >= n_nodes) return;

  float4 f[32];
  const float4* fv = reinterpret_cast<const float4*>(feat + (size_t)n * IN_FEATS);
#pragma unroll
  for (int i = 0; i < 32; ++i) f[i] = fv[i];

  float* hrow = h + (size_t)n * OUT_FEATS;
  for (int og = 0; og < 16; ++og) {
    const float4* __restrict__ w0 = reinterpret_cast<const float4*>(W + (size_t)(og*4+0) * IN_FEATS);
    const float4* __restrict__ w1 = reinterpret_cast<const float4*>(W + (size_t)(og*4+1) * IN_FEATS);
    const float4* __restrict__ w2 = reinterpret_cast<const float4*>(W + (size_t)(og*4+2) * IN_FEATS);
    const float4* __restrict__ w3 = reinterpret_cast<const float4*>(W + (size_t)(og*4+3) * IN_FEATS);
    float a0 = 0.f, a1 = 0.f, a2 = 0.f, a3 = 0.f;
#pragma unroll
    for (int j = 0; j < 32; ++j) {
      float4 fk = f[j];
      float4 x0 = w0[j], x1 = w1[j], x2 = w2[j], x3 = w3[j];
      a0 = fmaf(fk.x, x0.x, a0); a0 = fmaf(fk.y, x0.y, a0);
      a0 = fmaf(fk.z, x0.z, a0); a0 = fmaf(fk.w, x0.w, a0);
      a1 = fmaf(fk.x, x1.x, a1); a1 = fmaf(fk.y, x1.y, a1);
      a1 = fmaf(fk.z, x1.z, a1); a1 = fmaf(fk.w, x1.w, a1);
      a2 = fmaf(fk.x, x2.x, a2); a2 = fmaf(fk.y, x2.y, a2);
      a2 = fmaf(fk.z, x2.z, a2); a2 = fmaf(fk.w, x2.w, a2);
      a3 = fmaf(fk.x, x3.x, a3); a3 = fmaf(fk.y, x3.y, a3);
      a3 = fmaf(fk.z, x3.z, a3); a3 = fmaf(fk.w, x3.w, a3);
    }
    float4 out; out.x = a0; out.y = a1; out.z = a2; out.w = a3;
    *reinterpret_cast<float4*>(hrow + og * 4) = out;
  }
}

// ---------------------------------------------------------------------------
// Bucket sort pass A1: per-bucket edge counts (LDS hist, one flush per block)
// ---------------------------------------------------------------------------
__global__ __launch_bounds__(256)
void bhist_kernel(const int* __restrict__ dst, int* __restrict__ bcount,
                  int n_edges, int nbuck) {
  __shared__ int hist[512];
  const int t = threadIdx.x;
  for (int i = t; i < nbuck; i += 256) hist[i] = 0;
  __syncthreads();
  const int base = blockIdx.x * CHUNK;
#pragma unroll
  for (int i = 0; i < EPT; ++i) {
    int e = base + t + i * 256;
    if (e < n_edges) atomicAdd(&hist[dst[e] >> BSH], 1);
  }
  __syncthreads();
  for (int i = t; i < nbuck; i += 256)
    if (hist[i]) atomicAdd(&bcount[i], hist[i]);
}

// ---------------------------------------------------------------------------
// A2: exclusive scan of bucket counts (single block, nbuck <= 512)
// ---------------------------------------------------------------------------
__global__ void bscan_kernel(const int* __restrict__ bcount, int* __restrict__ bbase,
                             int* __restrict__ bcursor, int nbuck, int n_edges) {
  __shared__ int tmp[512];
  const int t = threadIdx.x;
  int v = (t < nbuck) ? bcount[t] : 0;
  tmp[t] = v;
  __syncthreads();
  for (int off = 1; off < 512; off <<= 1) {
    int x = (t >= off) ? tmp[t - off] : 0;
    __syncthreads();
    tmp[t] += x;
    __syncthreads();
  }
  if (t < nbuck) { int excl = tmp[t] - v; bbase[t] = excl; bcursor[t] = excl; }
  if (t == 0) bbase[nbuck] = n_edges;
}

// ---------------------------------------------------------------------------
// A3: scatter edges into bucket regions (per-block LDS hist -> contiguous
// chunk reservation -> ~16-edge contiguous runs).
// ---------------------------------------------------------------------------
__global__ __launch_bounds__(256)
void bscatter_kernel(const int* __restrict__ src, const int* __restrict__ dst,
                     int* __restrict__ bcursor, int2* __restrict__ tmpe,
                     int n_edges, int nbuck) {
  __shared__ int hist[512];
  __shared__ int basech[512];
  __shared__ int offs[512];
  const int t = threadIdx.x;
  const int base = blockIdx.x * CHUNK;
  for (int i = t; i < nbuck; i += 256) { hist[i] = 0; offs[i] = 0; }
  __syncthreads();
  int s16[EPT], d16[EPT];
#pragma unroll
  for (int i = 0; i < EPT; ++i) {
    int e = base + t + i * 256;
    if (e < n_edges) {
      s16[i] = src[e];
      d16[i] = dst[e];
      atomicAdd(&hist[d16[i] >> BSH], 1);
    } else {
      d16[i] = -1;
    }
  }
  __syncthreads();
  for (int i = t; i < nbuck; i += 256)
    if (hist[i]) basech[i] = atomicAdd(&bcursor[i], hist[i]);
  __syncthreads();
#pragma unroll
  for (int i = 0; i < EPT; ++i) {
    if (d16[i] >= 0) {
      int e = base + t + i * 256;
      int b = d16[i] >> BSH;
      int off = atomicAdd(&offs[b], 1);
      int2 v;
      v.x = s16[i];
      v.y = ((d16[i] & (BNODES - 1)) << EID_BITS) | e;
      tmpe[basech[b] + off] = v;
    }
  }
}

// ---------------------------------------------------------------------------
// B: one workgroup per bucket -> row_ptr + final CSR edata (src,eid).
// ---------------------------------------------------------------------------
__global__ __launch_bounds__(256)
void binB_kernel(const int2* __restrict__ tmpe, const int* __restrict__ bbase,
                 int2* __restrict__ edata, int* __restrict__ row_ptr,
                 int n_nodes, int n_edges) {
  __shared__ int cnt[BNODES];
  __shared__ int cur[BNODES];
  const int b = blockIdx.x;
  const int t = threadIdx.x;
  const int beg = bbase[b], end = bbase[b + 1];

  cnt[t] = 0;
  __syncthreads();
  for (int i = beg + t; i < end; i += 256)
    atomicAdd(&cnt[(tmpe[i].y >> EID_BITS) & (BNODES - 1)], 1);
  __syncthreads();

  int v = cnt[t];
  cur[t] = v;
  __syncthreads();
  for (int off = 1; off < BNODES; off <<= 1) {
    int x = (t >= off) ? cur[t - off] : 0;
    __syncthreads();
    cur[t] += x;
    __syncthreads();
  }
  int excl = cur[t] - v;
  int node = b * BNODES + t;
  if (node < n_nodes) row_ptr[node] = beg + excl;
  if (b == 0 && t == 0) row_ptr[n_nodes] = n_edges;
  __syncthreads();
  cur[t] = beg + excl;
  __syncthreads();

  for (int i = beg + t; i < end; i += 256) {
    int2 p = tmpe[i];
    int l = (p.y >> EID_BITS) & (BNODES - 1);
    int pos = atomicAdd(&cur[l], 1);
    int2 o;
    o.x = p.x;
    o.y = p.y & ((1 << EID_BITS) - 1);
    edata[pos] = o;
  }
}

// ---------------------------------------------------------------------------
// agg: wave per node, 4 edges in flight (lane = 16*eo + fo, float4 per lane)
// ---------------------------------------------------------------------------
__global__ void agg_kernel(const float* __restrict__ h, const int* __restrict__ row_ptr,
                           const int2* __restrict__ edata, float* __restrict__ h_agg,
                           int n_nodes) {
  int wid  = (blockIdx.x * blockDim.x + threadIdx.x) >> 6;
  int lane = threadIdx.x & 63;
  int eo = lane >> 4;
  int fo = lane & 15;
  if (wid >= n_nodes) return;
  int beg = row_ptr[wid], end = row_ptr[wid + 1];
  float4 acc = {0.f, 0.f, 0.f, 0.f};
  for (int i = beg + eo; i < end; i += 4) {
    int s = edata[i].x;
    float4 v = *reinterpret_cast<const float4*>(h + (size_t)s * OUT_FEATS + fo * 4);
    acc.x += v.x; acc.y += v.y; acc.z += v.z; acc.w += v.w;
  }
#pragma unroll
  for (int off = 16; off < 64; off <<= 1) {
    acc.x += __shfl_xor(acc.x, off, 64);
    acc.y += __shfl_xor(acc.y, off, 64);
    acc.z += __shfl_xor(acc.z, off, 64);
    acc.w += __shfl_xor(acc.w, off, 64);
  }
  if (eo == 0)
    *reinterpret_cast<float4*>(h_agg + (size_t)wid * OUT_FEATS + fo * 4) = acc;
}

// ---------------------------------------------------------------------------
// t_agg = tanh(h_agg), float4-vectorized streaming
// ---------------------------------------------------------------------------
__global__ void tanh_kernel(const float4* __restrict__ h_agg,
                            float4* __restrict__ t_agg, int n4) {
  int i = blockIdx.x * blockDim.x + threadIdx.x;
  if (i < n4) {
    float4 v = h_agg[i];
    float4 o;
    o.x = tanhf(v.x); o.y = tanhf(v.y); o.z = tanhf(v.z); o.w = tanhf(v.w);
    t_agg[i] = o;
  }
}

// ---------------------------------------------------------------------------
// P1 (edge order): scoreE[e] = leaky(dot(h_agg[src[e]], t_agg[dst[e]]));
// atomicMax m[dst] (monotone-uint). Wave = 4 edges x 16 lanes. Sequential
// writes; no CSR; 400K independent waves.
// ---------------------------------------------------------------------------
__global__ __launch_bounds__(256)
void score_kernel(const float* __restrict__ h_agg, const float* __restrict__ t_agg,
                  const int* __restrict__ src, const int* __restrict__ dst,
                  float* __restrict__ scoreE, unsigned* __restrict__ m,
                  int n_edges) {
  long long t = (long long)blockIdx.x * blockDim.x + threadIdx.x;
  int wv = (int)(t >> 6);
  int lane = (int)(t & 63);
  int eo = lane >> 4, fo = lane & 15;
  int e = wv * 4 + eo;
  if (e >= n_edges) return;
  int s = src[e], d = dst[e];
  float4 a = *reinterpret_cast<const float4*>(h_agg + (size_t)s * OUT_FEATS + fo * 4);
  float4 b = *reinterpret_cast<const float4*>(t_agg + (size_t)d * OUT_FEATS + fo * 4);
  float v = a.x * b.x + a.y * b.y + a.z * b.z + a.w * b.w;
#pragma unroll
  for (int off = 1; off < 16; off <<= 1) v += __shfl_xor(v, off, 64);
  if (fo == 0) {
    v = v > 0.f ? v : NEG_SLOPE * v;
    scoreE[e] = v;
    atomicMax(&m[d], f2u_ord(v));
  }
}

// ---------------------------------------------------------------------------
// P2 (edge order): s[dst] += exp(score - m[dst])
// ---------------------------------------------------------------------------
__global__ void sum_kernel(const float* __restrict__ scoreE,
                           const int* __restrict__ dst,
                           const unsigned* __restrict__ m,
                           float* __restrict__ ssum, int n_edges) {
  int e = blockIdx.x * blockDim.x + threadIdx.x;
  if (e < n_edges) {
    int d = dst[e];
    atomicAdd(&ssum[d], expf(scoreE[e] - u2f_ord(m[d])));
  }
}

// ---------------------------------------------------------------------------
// P3 (edge order): e_soft[e] = exp(score - m)/s  -- sequential write
// ---------------------------------------------------------------------------
__global__ void norm_kernel(const float* __restrict__ scoreE,
                            const int* __restrict__ dst,
                            const unsigned* __restrict__ m,
                            const float* __restrict__ ssum,
                            float* __restrict__ e_soft, int n_edges) {
  int e = blockIdx.x * blockDim.x + threadIdx.x;
  if (e < n_edges) {
    int d = dst[e];
    e_soft[e] = expf(scoreE[e] - u2f_ord(m[d])) / ssum[d];
  }
}

extern "C" void kernel_launch(void* const* d_in, const int* in_sizes, int n_in,
                              void* d_out, int out_size, void* d_ws, size_t ws_size,
                              hipStream_t stream) {
  const float* feat = (const float*)d_in[0];
  const float* W    = (const float*)d_in[1];
  const int*   src  = (const int*)d_in[2];
  const int*   dst  = (const int*)d_in[3];
  const int n_nodes = in_sizes[0] / IN_FEATS;
  const int n_edges = in_sizes[2];
  const int nbuck   = (n_nodes + BNODES - 1) >> BSH;   // <= 512

  // Output layout: [h_agg (N*64) | e_soft (E)]
  float* h_agg  = (float*)d_out;
  float* e_soft = (float*)d_out + (size_t)n_nodes * OUT_FEATS;

  // Workspace:
  // [h/t_agg (N*64 f32) | bcount(513) | bbase(513) | bcursor(512)
  //  | row_ptr(N+1, pad even) | tmpe (E int2) | edata (E int2)]
  // After binB, tmpe is dead: scoreE (E f32) + m (N u32) + s (N f32) alias it.
  float* h      = (float*)d_ws;              // later reused as t_agg
  int* bcount   = (int*)(h + (size_t)n_nodes * OUT_FEATS);
  int* bbase    = bcount + 513;
  int* bcursor  = bbase + 513;
  int* row_ptr  = bcursor + 512;
  size_t rp_pad = ((size_t)n_nodes + 2) & ~(size_t)1;
  int2* tmpe    = (int2*)(row_ptr + rp_pad);
  int2* edata   = tmpe + n_edges;

  float*    scoreE = (float*)tmpe;           // E floats
  unsigned* m      = (unsigned*)(scoreE + n_edges);  // N u32 (0 == -inf)
  float*    ssum   = (float*)(m + n_nodes);          // N f32

  const int eb2 = (n_edges + CHUNK - 1) / CHUNK;
  const int eb  = (n_edges + 255) / 256;
  const int wb  = (n_nodes * 64 + 255) / 256;

  hipMemsetAsync(bcount, 0, (size_t)nbuck * sizeof(int), stream);

  gemm_h_kernel<<<(n_nodes + 127) / 128, 128, 0, stream>>>(feat, W, h, n_nodes);

  bhist_kernel<<<eb2, 256, 0, stream>>>(dst, bcount, n_edges, nbuck);
  bscan_kernel<<<1, 512, 0, stream>>>(bcount, bbase, bcursor, nbuck, n_edges);
  bscatter_kernel<<<eb2, 256, 0, stream>>>(src, dst, bcursor, tmpe, n_edges, nbuck);
  binB_kernel<<<nbuck, 256, 0, stream>>>(tmpe, bbase, edata, row_ptr, n_nodes, n_edges);

  agg_kernel<<<wb, 256, 0, stream>>>(h, row_ptr, edata, h_agg, n_nodes);

  // h is dead now -> reuse as t_agg; tmpe is dead -> scoreE/m/ssum
  float* t_agg = h;
  int n4 = n_nodes * OUT_FEATS / 4;
  tanh_kernel<<<(n4 + 255) / 256, 256, 0, stream>>>((const float4*)h_agg,
                                                    (float4*)t_agg, n4);

  hipMemsetAsync(m, 0, (size_t)n_nodes * sizeof(unsigned), stream);   // -inf keys
  hipMemsetAsync(ssum, 0, (size_t)n_nodes * sizeof(float), stream);

  long long sc_threads = (long long)((n_edges + 3) / 4) * 64;
  int scb = (int)((sc_threads + 255) / 256);
  score_kernel<<<scb, 256, 0, stream>>>(h_agg, t_agg, src, dst, scoreE, m, n_edges);
  sum_kernel<<<eb, 256, 0, stream>>>(scoreE, dst, m, ssum, n_edges);
  norm_kernel<<<eb, 256, 0, stream>>>(scoreE, dst, m, ssum, e_soft, n_edges);
}

// Round 9
// 265.562 us; speedup vs baseline: 1.6918x; 1.6918x over previous
//
#include <hip/hip_runtime.h>
#include <math.h>

#define IN_FEATS 128
#define OUT_FEATS 64
#define NEG_SLOPE 0.2f
#define MAXD 256
#define BSH 8                      // bucket = dst >> 8 (256 nodes/bucket)
#define BNODES (1 << BSH)
#define CHUNK 4096                 // edges per block in bucket passes
#define EPT 16                     // edges per thread (CHUNK/256)
#define EID_BITS 21                // n_edges < 2^21
#define LDP 132                    // padded LDS row stride (floats)

// ---------------------------------------------------------------------------
// K1: h = feat @ W^T, LDS-tiled. Block = 256 threads, 64-node tile.
// feat tile (64x128) and W (64x128) staged in LDS, rows padded to 132 floats
// (feat reads conflict-free, W reads 2-way = free). Each thread: 4 nodes x
// 4 outputs, float4 k-chunks -> 8 ds_read_b128 + 64 FMA per chunk.
// ~65 VGPRs, no giant register arrays -> nothing for the allocator to spill.
// ---------------------------------------------------------------------------
__global__ __launch_bounds__(256)
void gemm_h_kernel(const float* __restrict__ feat,
                   const float* __restrict__ W,
                   float* __restrict__ h, int n_nodes) {
  __shared__ float fs[64 * LDP];
  __shared__ float ws[64 * LDP];
  const int t  = threadIdx.x;
  const int n0 = blockIdx.x * 64;

  // stage W (8192 floats, coalesced float4)
  for (int i = t; i < 64 * 32; i += 256) {
    int r = i >> 5, c4 = i & 31;
    float4 v = *reinterpret_cast<const float4*>(W + r * IN_FEATS + c4 * 4);
    *reinterpret_cast<float4*>(&ws[r * LDP + c4 * 4]) = v;
  }
  // stage feat tile (zero-pad past n_nodes)
  for (int i = t; i < 64 * 32; i += 256) {
    int r = i >> 5, c4 = i & 31;
    int n = n0 + r;
    float4 v = {0.f, 0.f, 0.f, 0.f};
    if (n < n_nodes)
      v = *reinterpret_cast<const float4*>(feat + (size_t)n * IN_FEATS + c4 * 4);
    *reinterpret_cast<float4*>(&fs[r * LDP + c4 * 4]) = v;
  }
  __syncthreads();

  const int l  = t & 63, q = t >> 6;
  const int ob = (l & 15) * 4;            // output base (4 outputs)
  const int nb = q * 16 + (l >> 4) * 4;   // node base (4 nodes)

  float acc[4][4] = {{0.f}};
  for (int k4 = 0; k4 < 32; ++k4) {
    float4 fr[4], wr[4];
#pragma unroll
    for (int i = 0; i < 4; ++i)
      fr[i] = *reinterpret_cast<const float4*>(&fs[(nb + i) * LDP + k4 * 4]);
#pragma unroll
    for (int j = 0; j < 4; ++j)
      wr[j] = *reinterpret_cast<const float4*>(&ws[(ob + j) * LDP + k4 * 4]);
#pragma unroll
    for (int i = 0; i < 4; ++i) {
#pragma unroll
      for (int j = 0; j < 4; ++j) {
        acc[i][j] = fmaf(fr[i].x, wr[j].x, acc[i][j]);
        acc[i][j] = fmaf(fr[i].y, wr[j].y, acc[i][j]);
        acc[i][j] = fmaf(fr[i].z, wr[j].z, acc[i][j]);
        acc[i][j] = fmaf(fr[i].w, wr[j].w, acc[i][j]);
      }
    }
  }

#pragma unroll
  for (int i = 0; i < 4; ++i) {
    int node = n0 + nb + i;
    if (node < n_nodes) {
      float4 v;
      v.x = acc[i][0]; v.y = acc[i][1]; v.z = acc[i][2]; v.w = acc[i][3];
      *reinterpret_cast<float4*>(h + (size_t)node * OUT_FEATS + ob) = v;
    }
  }
}

// ---------------------------------------------------------------------------
// Bucket sort pass A1: per-bucket edge counts (LDS hist, one flush per block)
// ---------------------------------------------------------------------------
__global__ __launch_bounds__(256)
void bhist_kernel(const int* __restrict__ dst, int* __restrict__ bcount,
                  int n_edges, int nbuck) {
  __shared__ int hist[512];
  const int t = threadIdx.x;
  for (int i = t; i < nbuck; i += 256) hist[i] = 0;
  __syncthreads();
  const int base = blockIdx.x * CHUNK;
#pragma unroll
  for (int i = 0; i < EPT; ++i) {
    int e = base + t + i * 256;
    if (e < n_edges) atomicAdd(&hist[dst[e] >> BSH], 1);
  }
  __syncthreads();
  for (int i = t; i < nbuck; i += 256)
    if (hist[i]) atomicAdd(&bcount[i], hist[i]);
}

// ---------------------------------------------------------------------------
// A2: exclusive scan of bucket counts (single block, nbuck <= 512)
// ---------------------------------------------------------------------------
__global__ void bscan_kernel(const int* __restrict__ bcount, int* __restrict__ bbase,
                             int* __restrict__ bcursor, int nbuck, int n_edges) {
  __shared__ int tmp[512];
  const int t = threadIdx.x;
  int v = (t < nbuck) ? bcount[t] : 0;
  tmp[t] = v;
  __syncthreads();
  for (int off = 1; off < 512; off <<= 1) {
    int x = (t >= off) ? tmp[t - off] : 0;
    __syncthreads();
    tmp[t] += x;
    __syncthreads();
  }
  if (t < nbuck) { int excl = tmp[t] - v; bbase[t] = excl; bcursor[t] = excl; }
  if (t == 0) bbase[nbuck] = n_edges;
}

// ---------------------------------------------------------------------------
// A3: scatter edges into bucket regions (per-block LDS hist -> contiguous
// chunk reservation -> ~16-edge contiguous runs).
// ---------------------------------------------------------------------------
__global__ __launch_bounds__(256)
void bscatter_kernel(const int* __restrict__ src, const int* __restrict__ dst,
                     int* __restrict__ bcursor, int2* __restrict__ tmpe,
                     int n_edges, int nbuck) {
  __shared__ int hist[512];
  __shared__ int basech[512];
  __shared__ int offs[512];
  const int t = threadIdx.x;
  const int base = blockIdx.x * CHUNK;
  for (int i = t; i < nbuck; i += 256) { hist[i] = 0; offs[i] = 0; }
  __syncthreads();
  int s16[EPT], d16[EPT];
#pragma unroll
  for (int i = 0; i < EPT; ++i) {
    int e = base + t + i * 256;
    if (e < n_edges) {
      s16[i] = src[e];
      d16[i] = dst[e];
      atomicAdd(&hist[d16[i] >> BSH], 1);
    } else {
      d16[i] = -1;
    }
  }
  __syncthreads();
  for (int i = t; i < nbuck; i += 256)
    if (hist[i]) basech[i] = atomicAdd(&bcursor[i], hist[i]);
  __syncthreads();
#pragma unroll
  for (int i = 0; i < EPT; ++i) {
    if (d16[i] >= 0) {
      int e = base + t + i * 256;
      int b = d16[i] >> BSH;
      int off = atomicAdd(&offs[b], 1);
      int2 v;
      v.x = s16[i];
      v.y = ((d16[i] & (BNODES - 1)) << EID_BITS) | e;
      tmpe[basech[b] + off] = v;
    }
  }
}

// ---------------------------------------------------------------------------
// B: one workgroup per bucket -> row_ptr + final CSR edata (src,eid).
// ---------------------------------------------------------------------------
__global__ __launch_bounds__(256)
void binB_kernel(const int2* __restrict__ tmpe, const int* __restrict__ bbase,
                 int2* __restrict__ edata, int* __restrict__ row_ptr,
                 int n_nodes, int n_edges) {
  __shared__ int cnt[BNODES];
  __shared__ int cur[BNODES];
  const int b = blockIdx.x;
  const int t = threadIdx.x;
  const int beg = bbase[b], end = bbase[b + 1];

  cnt[t] = 0;
  __syncthreads();
  for (int i = beg + t; i < end; i += 256)
    atomicAdd(&cnt[(tmpe[i].y >> EID_BITS) & (BNODES - 1)], 1);
  __syncthreads();

  int v = cnt[t];
  cur[t] = v;
  __syncthreads();
  for (int off = 1; off < BNODES; off <<= 1) {
    int x = (t >= off) ? cur[t - off] : 0;
    __syncthreads();
    cur[t] += x;
    __syncthreads();
  }
  int excl = cur[t] - v;
  int node = b * BNODES + t;
  if (node < n_nodes) row_ptr[node] = beg + excl;
  if (b == 0 && t == 0) row_ptr[n_nodes] = n_edges;
  __syncthreads();
  cur[t] = beg + excl;
  __syncthreads();

  for (int i = beg + t; i < end; i += 256) {
    int2 p = tmpe[i];
    int l = (p.y >> EID_BITS) & (BNODES - 1);
    int pos = atomicAdd(&cur[l], 1);
    int2 o;
    o.x = p.x;
    o.y = p.y & ((1 << EID_BITS) - 1);
    edata[pos] = o;
  }
}

// ---------------------------------------------------------------------------
// agg: wave per node, 4 edges in flight (lane = 16*eo + fo, float4 per lane)
// ---------------------------------------------------------------------------
__global__ void agg_kernel(const float* __restrict__ h, const int* __restrict__ row_ptr,
                           const int2* __restrict__ edata, float* __restrict__ h_agg,
                           int n_nodes) {
  int wid  = (blockIdx.x * blockDim.x + threadIdx.x) >> 6;
  int lane = threadIdx.x & 63;
  int eo = lane >> 4;
  int fo = lane & 15;
  if (wid >= n_nodes) return;
  int beg = row_ptr[wid], end = row_ptr[wid + 1];
  float4 acc = {0.f, 0.f, 0.f, 0.f};
  for (int i = beg + eo; i < end; i += 4) {
    int s = edata[i].x;
    float4 v = *reinterpret_cast<const float4*>(h + (size_t)s * OUT_FEATS + fo * 4);
    acc.x += v.x; acc.y += v.y; acc.z += v.z; acc.w += v.w;
  }
#pragma unroll
  for (int off = 16; off < 64; off <<= 1) {
    acc.x += __shfl_xor(acc.x, off, 64);
    acc.y += __shfl_xor(acc.y, off, 64);
    acc.z += __shfl_xor(acc.z, off, 64);
    acc.w += __shfl_xor(acc.w, off, 64);
  }
  if (eo == 0)
    *reinterpret_cast<float4*>(h_agg + (size_t)wid * OUT_FEATS + fo * 4) = acc;
}

// ---------------------------------------------------------------------------
// fused per-node edge softmax, 4 edges in flight (R7-proven version).
// ---------------------------------------------------------------------------
__global__ __launch_bounds__(256)
void softmax_kernel(const float* __restrict__ h_agg, const int* __restrict__ row_ptr,
                    const int2* __restrict__ edata,
                    float* __restrict__ e_soft, int n_nodes) {
  __shared__ float ebuf[4][MAXD];
  int wid  = (blockIdx.x * blockDim.x + threadIdx.x) >> 6;
  int lane = threadIdx.x & 63;
  int lw   = threadIdx.x >> 6;
  int eo = lane >> 4;
  int fo = lane & 15;
  if (wid >= n_nodes) return;
  int beg = row_ptr[wid], end = row_ptr[wid + 1];
  int deg = end - beg;
  if (deg == 0) return;

  float4 td = *reinterpret_cast<const float4*>(h_agg + (size_t)wid * OUT_FEATS + fo * 4);
  float4 t4;
  t4.x = tanhf(td.x); t4.y = tanhf(td.y); t4.z = tanhf(td.z); t4.w = tanhf(td.w);

  if (deg <= MAXD) {
    for (int i0 = 0; i0 < deg; i0 += 4) {
      int e = i0 + eo;
      int idx = beg + (e < deg ? e : deg - 1);  // clamp; dup gather harmless
      int s = edata[idx].x;
      float4 v = *reinterpret_cast<const float4*>(h_agg + (size_t)s * OUT_FEATS + fo * 4);
      float d = v.x * t4.x + v.y * t4.y + v.z * t4.z + v.w * t4.w;
#pragma unroll
      for (int off = 1; off < 16; off <<= 1) d += __shfl_xor(d, off, 64);
      if (fo == 0 && e < deg) {
        d = d > 0.f ? d : NEG_SLOPE * d;
        ebuf[lw][e] = d;
      }
    }
    float mx = -INFINITY;
    for (int i = lane; i < deg; i += 64) mx = fmaxf(mx, ebuf[lw][i]);
#pragma unroll
    for (int off = 32; off > 0; off >>= 1) mx = fmaxf(mx, __shfl_xor(mx, off, 64));
    float sum = 0.f;
    for (int i = lane; i < deg; i += 64) {
      float ex = expf(ebuf[lw][i] - mx);
      ebuf[lw][i] = ex;
      sum += ex;
    }
#pragma unroll
    for (int off = 32; off > 0; off >>= 1) sum += __shfl_xor(sum, off, 64);
    float inv = 1.f / sum;
    for (int i = lane; i < deg; i += 64) e_soft[edata[beg + i].y] = ebuf[lw][i] * inv;
  } else {
    // recompute fallback (statistically never hit with Poisson(16) degrees)
    float mx = -INFINITY;
    for (int i0 = 0; i0 < deg; i0 += 4) {
      int e = i0 + eo;
      int idx = beg + (e < deg ? e : deg - 1);
      int s = edata[idx].x;
      float4 v = *reinterpret_cast<const float4*>(h_agg + (size_t)s * OUT_FEATS + fo * 4);
      float d = v.x * t4.x + v.y * t4.y + v.z * t4.z + v.w * t4.w;
#pragma unroll
      for (int off = 1; off < 16; off <<= 1) d += __shfl_xor(d, off, 64);
      d = d > 0.f ? d : NEG_SLOPE * d;
      if (e >= deg) d = -INFINITY;
#pragma unroll
      for (int off = 16; off < 64; off <<= 1) d = fmaxf(d, __shfl_xor(d, off, 64));
      mx = fmaxf(mx, d);
    }
    float sum = 0.f;
    for (int i0 = 0; i0 < deg; i0 += 4) {
      int e = i0 + eo;
      int idx = beg + (e < deg ? e : deg - 1);
      int s = edata[idx].x;
      float4 v = *reinterpret_cast<const float4*>(h_agg + (size_t)s * OUT_FEATS + fo * 4);
      float d = v.x * t4.x + v.y * t4.y + v.z * t4.z + v.w * t4.w;
#pragma unroll
      for (int off = 1; off < 16; off <<= 1) d += __shfl_xor(d, off, 64);
      d = d > 0.f ? d : NEG_SLOPE * d;
      float ex = (e < deg) ? expf(d - mx) : 0.f;
#pragma unroll
      for (int off = 16; off < 64; off <<= 1) ex += __shfl_xor(ex, off, 64);
      sum += ex;
    }
    float inv = 1.f / sum;
    for (int i0 = 0; i0 < deg; i0 += 4) {
      int e = i0 + eo;
      int idx = beg + (e < deg ? e : deg - 1);
      int s = edata[idx].x;
      float4 v = *reinterpret_cast<const float4*>(h_agg + (size_t)s * OUT_FEATS + fo * 4);
      float d = v.x * t4.x + v.y * t4.y + v.z * t4.z + v.w * t4.w;
#pragma unroll
      for (int off = 1; off < 16; off <<= 1) d += __shfl_xor(d, off, 64);
      d = d > 0.f ? d : NEG_SLOPE * d;
      if (fo == 0 && e < deg) e_soft[edata[idx].y] = expf(d - mx) * inv;
    }
  }
}

extern "C" void kernel_launch(void* const* d_in, const int* in_sizes, int n_in,
                              void* d_out, int out_size, void* d_ws, size_t ws_size,
                              hipStream_t stream) {
  const float* feat = (const float*)d_in[0];
  const float* W    = (const float*)d_in[1];
  const int*   src  = (const int*)d_in[2];
  const int*   dst  = (const int*)d_in[3];
  const int n_nodes = in_sizes[0] / IN_FEATS;
  const int n_edges = in_sizes[2];
  const int nbuck   = (n_nodes + BNODES - 1) >> BSH;   // <= 512

  // Output layout: [h_agg (N*64) | e_soft (E)]
  float* h_agg  = (float*)d_out;
  float* e_soft = (float*)d_out + (size_t)n_nodes * OUT_FEATS;

  // Workspace:
  // [h (N*64 f32) | bcount(513) | bbase(513) | bcursor(512)
  //  | row_ptr(N+1, pad even) | tmpe (E int2) | edata (E int2)]
  float* h      = (float*)d_ws;
  int* bcount   = (int*)(h + (size_t)n_nodes * OUT_FEATS);
  int* bbase    = bcount + 513;
  int* bcursor  = bbase + 513;
  int* row_ptr  = bcursor + 512;
  size_t rp_pad = ((size_t)n_nodes + 2) & ~(size_t)1;
  int2* tmpe    = (int2*)(row_ptr + rp_pad);
  int2* edata   = tmpe + n_edges;

  const int eb2 = (n_edges + CHUNK - 1) / CHUNK;
  const int wb  = (n_nodes * 64 + 255) / 256;

  hipMemsetAsync(bcount, 0, (size_t)nbuck * sizeof(int), stream);

  gemm_h_kernel<<<(n_nodes + 63) / 64, 256, 0, stream>>>(feat, W, h, n_nodes);

  bhist_kernel<<<eb2, 256, 0, stream>>>(dst, bcount, n_edges, nbuck);
  bscan_kernel<<<1, 512, 0, stream>>>(bcount, bbase, bcursor, nbuck, n_edges);
  bscatter_kernel<<<eb2, 256, 0, stream>>>(src, dst, bcursor, tmpe, n_edges, nbuck);
  binB_kernel<<<nbuck, 256, 0, stream>>>(tmpe, bbase, edata, row_ptr, n_nodes, n_edges);

  agg_kernel<<<wb, 256, 0, stream>>>(h, row_ptr, edata, h_agg, n_nodes);
  softmax_kernel<<<wb, 256, 0, stream>>>(h_agg, row_ptr, edata, e_soft, n_nodes);
}

// Round 10
// 224.380 us; speedup vs baseline: 2.0023x; 1.1835x over previous
//
#include <hip/hip_runtime.h>
#include <math.h>

#define IN_FEATS 128
#define OUT_FEATS 64
#define NEG_SLOPE 0.2f
#define MAXD 256
#define BSH 8                      // bucket = dst >> 8 (256 nodes/bucket)
#define BNODES (1 << BSH)
#define CHUNK 4096                 // edges per block in bucket passes
#define EPT 16                     // edges per thread (CHUNK/256)
#define EID_BITS 21                // n_edges < 2^21
#define LDP 132                    // padded LDS row stride (floats)

// bf16 helpers: packed pair in a uint (lo = even feat, hi = odd feat)
__device__ __forceinline__ float bf_lo(unsigned u) { return __uint_as_float(u << 16); }
__device__ __forceinline__ float bf_hi(unsigned u) { return __uint_as_float(u & 0xffff0000u); }
__device__ __forceinline__ unsigned short f2bf(float f) {
  unsigned x = __float_as_uint(f);
  x += 0x7fff + ((x >> 16) & 1);          // round to nearest even
  return (unsigned short)(x >> 16);
}

// ---------------------------------------------------------------------------
// K1: h16 = bf16(feat @ W^T), LDS-tiled (R9-proven). Only agg consumes h, so
// emit bf16 directly: write 25.6->12.8 MB, agg gather volume halves.
// ---------------------------------------------------------------------------
__global__ __launch_bounds__(256)
void gemm_h_kernel(const float* __restrict__ feat,
                   const float* __restrict__ W,
                   unsigned short* __restrict__ h16, int n_nodes) {
  __shared__ float fs[64 * LDP];
  __shared__ float ws[64 * LDP];
  const int t  = threadIdx.x;
  const int n0 = blockIdx.x * 64;

  for (int i = t; i < 64 * 32; i += 256) {
    int r = i >> 5, c4 = i & 31;
    float4 v = *reinterpret_cast<const float4*>(W + r * IN_FEATS + c4 * 4);
    *reinterpret_cast<float4*>(&ws[r * LDP + c4 * 4]) = v;
  }
  for (int i = t; i < 64 * 32; i += 256) {
    int r = i >> 5, c4 = i & 31;
    int n = n0 + r;
    float4 v = {0.f, 0.f, 0.f, 0.f};
    if (n < n_nodes)
      v = *reinterpret_cast<const float4*>(feat + (size_t)n * IN_FEATS + c4 * 4);
    *reinterpret_cast<float4*>(&fs[r * LDP + c4 * 4]) = v;
  }
  __syncthreads();

  const int l  = t & 63, q = t >> 6;
  const int ob = (l & 15) * 4;            // output base (4 outputs)
  const int nb = q * 16 + (l >> 4) * 4;   // node base (4 nodes)

  float acc[4][4] = {{0.f}};
  for (int k4 = 0; k4 < 32; ++k4) {
    float4 fr[4], wr[4];
#pragma unroll
    for (int i = 0; i < 4; ++i)
      fr[i] = *reinterpret_cast<const float4*>(&fs[(nb + i) * LDP + k4 * 4]);
#pragma unroll
    for (int j = 0; j < 4; ++j)
      wr[j] = *reinterpret_cast<const float4*>(&ws[(ob + j) * LDP + k4 * 4]);
#pragma unroll
    for (int i = 0; i < 4; ++i) {
#pragma unroll
      for (int j = 0; j < 4; ++j) {
        acc[i][j] = fmaf(fr[i].x, wr[j].x, acc[i][j]);
        acc[i][j] = fmaf(fr[i].y, wr[j].y, acc[i][j]);
        acc[i][j] = fmaf(fr[i].z, wr[j].z, acc[i][j]);
        acc[i][j] = fmaf(fr[i].w, wr[j].w, acc[i][j]);
      }
    }
  }

#pragma unroll
  for (int i = 0; i < 4; ++i) {
    int node = n0 + nb + i;
    if (node < n_nodes) {
      ushort4 o;
      o.x = f2bf(acc[i][0]); o.y = f2bf(acc[i][1]);
      o.z = f2bf(acc[i][2]); o.w = f2bf(acc[i][3]);
      *reinterpret_cast<ushort4*>(h16 + (size_t)node * OUT_FEATS + ob) = o;
    }
  }
}

// ---------------------------------------------------------------------------
// Bucket sort pass A1: per-bucket edge counts
// ---------------------------------------------------------------------------
__global__ __launch_bounds__(256)
void bhist_kernel(const int* __restrict__ dst, int* __restrict__ bcount,
                  int n_edges, int nbuck) {
  __shared__ int hist[512];
  const int t = threadIdx.x;
  for (int i = t; i < nbuck; i += 256) hist[i] = 0;
  __syncthreads();
  const int base = blockIdx.x * CHUNK;
#pragma unroll
  for (int i = 0; i < EPT; ++i) {
    int e = base + t + i * 256;
    if (e < n_edges) atomicAdd(&hist[dst[e] >> BSH], 1);
  }
  __syncthreads();
  for (int i = t; i < nbuck; i += 256)
    if (hist[i]) atomicAdd(&bcount[i], hist[i]);
}

// ---------------------------------------------------------------------------
// A2: exclusive scan of bucket counts
// ---------------------------------------------------------------------------
__global__ void bscan_kernel(const int* __restrict__ bcount, int* __restrict__ bbase,
                             int* __restrict__ bcursor, int nbuck, int n_edges) {
  __shared__ int tmp[512];
  const int t = threadIdx.x;
  int v = (t < nbuck) ? bcount[t] : 0;
  tmp[t] = v;
  __syncthreads();
  for (int off = 1; off < 512; off <<= 1) {
    int x = (t >= off) ? tmp[t - off] : 0;
    __syncthreads();
    tmp[t] += x;
    __syncthreads();
  }
  if (t < nbuck) { int excl = tmp[t] - v; bbase[t] = excl; bcursor[t] = excl; }
  if (t == 0) bbase[nbuck] = n_edges;
}

// ---------------------------------------------------------------------------
// A3: scatter edges into bucket regions
// ---------------------------------------------------------------------------
__global__ __launch_bounds__(256)
void bscatter_kernel(const int* __restrict__ src, const int* __restrict__ dst,
                     int* __restrict__ bcursor, int2* __restrict__ tmpe,
                     int n_edges, int nbuck) {
  __shared__ int hist[512];
  __shared__ int basech[512];
  __shared__ int offs[512];
  const int t = threadIdx.x;
  const int base = blockIdx.x * CHUNK;
  for (int i = t; i < nbuck; i += 256) { hist[i] = 0; offs[i] = 0; }
  __syncthreads();
  int s16a[EPT], d16a[EPT];
#pragma unroll
  for (int i = 0; i < EPT; ++i) {
    int e = base + t + i * 256;
    if (e < n_edges) {
      s16a[i] = src[e];
      d16a[i] = dst[e];
      atomicAdd(&hist[d16a[i] >> BSH], 1);
    } else {
      d16a[i] = -1;
    }
  }
  __syncthreads();
  for (int i = t; i < nbuck; i += 256)
    if (hist[i]) basech[i] = atomicAdd(&bcursor[i], hist[i]);
  __syncthreads();
#pragma unroll
  for (int i = 0; i < EPT; ++i) {
    if (d16a[i] >= 0) {
      int e = base + t + i * 256;
      int b = d16a[i] >> BSH;
      int off = atomicAdd(&offs[b], 1);
      int2 v;
      v.x = s16a[i];
      v.y = ((d16a[i] & (BNODES - 1)) << EID_BITS) | e;
      tmpe[basech[b] + off] = v;
    }
  }
}

// ---------------------------------------------------------------------------
// B: one workgroup per bucket -> row_ptr + final CSR edata (src,eid).
// ---------------------------------------------------------------------------
__global__ __launch_bounds__(256)
void binB_kernel(const int2* __restrict__ tmpe, const int* __restrict__ bbase,
                 int2* __restrict__ edata, int* __restrict__ row_ptr,
                 int n_nodes, int n_edges) {
  __shared__ int cnt[BNODES];
  __shared__ int cur[BNODES];
  const int b = blockIdx.x;
  const int t = threadIdx.x;
  const int beg = bbase[b], end = bbase[b + 1];

  cnt[t] = 0;
  __syncthreads();
  for (int i = beg + t; i < end; i += 256)
    atomicAdd(&cnt[(tmpe[i].y >> EID_BITS) & (BNODES - 1)], 1);
  __syncthreads();

  int v = cnt[t];
  cur[t] = v;
  __syncthreads();
  for (int off = 1; off < BNODES; off <<= 1) {
    int x = (t >= off) ? cur[t - off] : 0;
    __syncthreads();
    cur[t] += x;
    __syncthreads();
  }
  int excl = cur[t] - v;
  int node = b * BNODES + t;
  if (node < n_nodes) row_ptr[node] = beg + excl;
  if (b == 0 && t == 0) row_ptr[n_nodes] = n_edges;
  __syncthreads();
  cur[t] = beg + excl;
  __syncthreads();

  for (int i = beg + t; i < end; i += 256) {
    int2 p = tmpe[i];
    int l = (p.y >> EID_BITS) & (BNODES - 1);
    int pos = atomicAdd(&cur[l], 1);
    int2 o;
    o.x = p.x;
    o.y = p.y & ((1 << EID_BITS) - 1);
    edata[pos] = o;
  }
}

// ---------------------------------------------------------------------------
// agg: wave per node, 8 edges in flight (lane = 8*eo+fo, bf16x8 per lane),
// f32 accumulate; gather volume halved vs f32 rows.
// ---------------------------------------------------------------------------
__global__ void agg_kernel(const unsigned* __restrict__ h16u,  // rows of 32 uints
                           const int* __restrict__ row_ptr,
                           const int2* __restrict__ edata, float* __restrict__ h_agg,
                           int n_nodes) {
  int wid  = (blockIdx.x * blockDim.x + threadIdx.x) >> 6;
  int lane = threadIdx.x & 63;
  int eo = lane >> 3;   // edge slot in group of 8
  int fo = lane & 7;    // bf16x8 slot in row
  if (wid >= n_nodes) return;
  int beg = row_ptr[wid], end = row_ptr[wid + 1];
  float acc[8] = {0.f, 0.f, 0.f, 0.f, 0.f, 0.f, 0.f, 0.f};
  for (int i = beg + eo; i < end; i += 8) {
    int s = edata[i].x;
    uint4 v = *reinterpret_cast<const uint4*>(h16u + (size_t)s * 32 + fo * 4);
    acc[0] += bf_lo(v.x); acc[1] += bf_hi(v.x);
    acc[2] += bf_lo(v.y); acc[3] += bf_hi(v.y);
    acc[4] += bf_lo(v.z); acc[5] += bf_hi(v.z);
    acc[6] += bf_lo(v.w); acc[7] += bf_hi(v.w);
  }
#pragma unroll
  for (int off = 8; off < 64; off <<= 1) {
#pragma unroll
    for (int j = 0; j < 8; ++j) acc[j] += __shfl_xor(acc[j], off, 64);
  }
  if (eo == 0) {
    float4 a, b;
    a.x = acc[0]; a.y = acc[1]; a.z = acc[2]; a.w = acc[3];
    b.x = acc[4]; b.y = acc[5]; b.z = acc[6]; b.w = acc[7];
    float* out = h_agg + (size_t)wid * OUT_FEATS + fo * 8;
    *reinterpret_cast<float4*>(out) = a;
    *reinterpret_cast<float4*>(out + 4) = b;
  }
}

// ---------------------------------------------------------------------------
// t16 = bf16(tanh(h_agg)), a16 = bf16(h_agg) — one streaming pass, hoists
// tanh out of softmax (was recomputed with 4x lane redundancy per wave).
// ---------------------------------------------------------------------------
__global__ void tanh_kernel(const float4* __restrict__ h_agg,
                            ushort4* __restrict__ t16, ushort4* __restrict__ a16,
                            int n4) {
  int i = blockIdx.x * blockDim.x + threadIdx.x;
  if (i < n4) {
    float4 v = h_agg[i];
    ushort4 a;
    a.x = f2bf(v.x); a.y = f2bf(v.y); a.z = f2bf(v.z); a.w = f2bf(v.w);
    a16[i] = a;
    ushort4 o;
    o.x = f2bf(tanhf(v.x)); o.y = f2bf(tanhf(v.y));
    o.z = f2bf(tanhf(v.z)); o.w = f2bf(tanhf(v.w));
    t16[i] = o;
  }
}

// ---------------------------------------------------------------------------
// fused per-node edge softmax, 8 edges in flight over bf16 rows.
// ---------------------------------------------------------------------------
__global__ __launch_bounds__(256)
void softmax_kernel(const unsigned* __restrict__ a16u, const unsigned* __restrict__ t16u,
                    const int* __restrict__ row_ptr, const int2* __restrict__ edata,
                    float* __restrict__ e_soft, int n_nodes) {
  __shared__ float ebuf[4][MAXD];
  int wid  = (blockIdx.x * blockDim.x + threadIdx.x) >> 6;
  int lane = threadIdx.x & 63;
  int lw   = threadIdx.x >> 6;
  int eo = lane >> 3;
  int fo = lane & 7;
  if (wid >= n_nodes) return;
  int beg = row_ptr[wid], end = row_ptr[wid + 1];
  int deg = end - beg;
  if (deg == 0) return;

  // this node's tanh slice (8 feats per lane; same across eo groups)
  uint4 tv = *reinterpret_cast<const uint4*>(t16u + (size_t)wid * 32 + fo * 4);
  float tt[8];
  tt[0] = bf_lo(tv.x); tt[1] = bf_hi(tv.x);
  tt[2] = bf_lo(tv.y); tt[3] = bf_hi(tv.y);
  tt[4] = bf_lo(tv.z); tt[5] = bf_hi(tv.z);
  tt[6] = bf_lo(tv.w); tt[7] = bf_hi(tv.w);

  if (deg <= MAXD) {
    for (int i0 = 0; i0 < deg; i0 += 8) {
      int e = i0 + eo;
      int idx = beg + (e < deg ? e : deg - 1);  // clamp; dup gather harmless
      int s = edata[idx].x;
      uint4 av = *reinterpret_cast<const uint4*>(a16u + (size_t)s * 32 + fo * 4);
      float d = tt[0] * bf_lo(av.x) + tt[1] * bf_hi(av.x)
              + tt[2] * bf_lo(av.y) + tt[3] * bf_hi(av.y)
              + tt[4] * bf_lo(av.z) + tt[5] * bf_hi(av.z)
              + tt[6] * bf_lo(av.w) + tt[7] * bf_hi(av.w);
#pragma unroll
      for (int off = 1; off < 8; off <<= 1) d += __shfl_xor(d, off, 64);
      if (fo == 0 && e < deg) {
        d = d > 0.f ? d : NEG_SLOPE * d;
        ebuf[lw][e] = d;
      }
    }
    float mx = -INFINITY;
    for (int i = lane; i < deg; i += 64) mx = fmaxf(mx, ebuf[lw][i]);
#pragma unroll
    for (int off = 32; off > 0; off >>= 1) mx = fmaxf(mx, __shfl_xor(mx, off, 64));
    float sum = 0.f;
    for (int i = lane; i < deg; i += 64) {
      float ex = expf(ebuf[lw][i] - mx);
      ebuf[lw][i] = ex;
      sum += ex;
    }
#pragma unroll
    for (int off = 32; off > 0; off >>= 1) sum += __shfl_xor(sum, off, 64);
    float inv = 1.f / sum;
    for (int i = lane; i < deg; i += 64) e_soft[edata[beg + i].y] = ebuf[lw][i] * inv;
  } else {
    // recompute fallback (statistically never hit with Poisson(16) degrees)
    float mx = -INFINITY;
    for (int i0 = 0; i0 < deg; i0 += 8) {
      int e = i0 + eo;
      int idx = beg + (e < deg ? e : deg - 1);
      int s = edata[idx].x;
      uint4 av = *reinterpret_cast<const uint4*>(a16u + (size_t)s * 32 + fo * 4);
      float d = tt[0] * bf_lo(av.x) + tt[1] * bf_hi(av.x)
              + tt[2] * bf_lo(av.y) + tt[3] * bf_hi(av.y)
              + tt[4] * bf_lo(av.z) + tt[5] * bf_hi(av.z)
              + tt[6] * bf_lo(av.w) + tt[7] * bf_hi(av.w);
#pragma unroll
      for (int off = 1; off < 8; off <<= 1) d += __shfl_xor(d, off, 64);
      d = d > 0.f ? d : NEG_SLOPE * d;
      if (e >= deg) d = -INFINITY;
#pragma unroll
      for (int off = 8; off < 64; off <<= 1) d = fmaxf(d, __shfl_xor(d, off, 64));
      mx = fmaxf(mx, d);
    }
    float sum = 0.f;
    for (int i0 = 0; i0 < deg; i0 += 8) {
      int e = i0 + eo;
      int idx = beg + (e < deg ? e : deg - 1);
      int s = edata[idx].x;
      uint4 av = *reinterpret_cast<const uint4*>(a16u + (size_t)s * 32 + fo * 4);
      float d = tt[0] * bf_lo(av.x) + tt[1] * bf_hi(av.x)
              + tt[2] * bf_lo(av.y) + tt[3] * bf_hi(av.y)
              + tt[4] * bf_lo(av.z) + tt[5] * bf_hi(av.z)
              + tt[6] * bf_lo(av.w) + tt[7] * bf_hi(av.w);
#pragma unroll
      for (int off = 1; off < 8; off <<= 1) d += __shfl_xor(d, off, 64);
      d = d > 0.f ? d : NEG_SLOPE * d;
      float ex = (e < deg) ? expf(d - mx) : 0.f;
#pragma unroll
      for (int off = 8; off < 64; off <<= 1) ex += __shfl_xor(ex, off, 64);
      sum += ex;
    }
    float inv = 1.f / sum;
    for (int i0 = 0; i0 < deg; i0 += 8) {
      int e = i0 + eo;
      int idx = beg + (e < deg ? e : deg - 1);
      int s = edata[idx].x;
      uint4 av = *reinterpret_cast<const uint4*>(a16u + (size_t)s * 32 + fo * 4);
      float d = tt[0] * bf_lo(av.x) + tt[1] * bf_hi(av.x)
              + tt[2] * bf_lo(av.y) + tt[3] * bf_hi(av.y)
              + tt[4] * bf_lo(av.z) + tt[5] * bf_hi(av.z)
              + tt[6] * bf_lo(av.w) + tt[7] * bf_hi(av.w);
#pragma unroll
      for (int off = 1; off < 8; off <<= 1) d += __shfl_xor(d, off, 64);
      d = d > 0.f ? d : NEG_SLOPE * d;
      if (fo == 0 && e < deg) e_soft[edata[idx].y] = expf(d - mx) * inv;
    }
  }
}

extern "C" void kernel_launch(void* const* d_in, const int* in_sizes, int n_in,
                              void* d_out, int out_size, void* d_ws, size_t ws_size,
                              hipStream_t stream) {
  const float* feat = (const float*)d_in[0];
  const float* W    = (const float*)d_in[1];
  const int*   src  = (const int*)d_in[2];
  const int*   dst  = (const int*)d_in[3];
  const int n_nodes = in_sizes[0] / IN_FEATS;
  const int n_edges = in_sizes[2];
  const int nbuck   = (n_nodes + BNODES - 1) >> BSH;   // <= 512

  // Output layout: [h_agg (N*64) | e_soft (E)]
  float* h_agg  = (float*)d_out;
  float* e_soft = (float*)d_out + (size_t)n_nodes * OUT_FEATS;

  // Workspace (same 25.6 MB head region as before, now split bf16):
  // [h16/t16 (N*64 bf16) | a16 (N*64 bf16) | bcount(513) | bbase(513)
  //  | bcursor(512) | row_ptr(N+1 pad) | tmpe (E int2) | edata (E int2)]
  unsigned short* h16 = (unsigned short*)d_ws;         // later reused as t16
  unsigned short* a16 = h16 + (size_t)n_nodes * OUT_FEATS;
  int* bcount   = (int*)(a16 + (size_t)n_nodes * OUT_FEATS);
  int* bbase    = bcount + 513;
  int* bcursor  = bbase + 513;
  int* row_ptr  = bcursor + 512;
  size_t rp_pad = ((size_t)n_nodes + 2) & ~(size_t)1;
  int2* tmpe    = (int2*)(row_ptr + rp_pad);
  int2* edata   = tmpe + n_edges;

  const int eb2 = (n_edges + CHUNK - 1) / CHUNK;
  const int wb  = (n_nodes * 64 + 255) / 256;

  hipMemsetAsync(bcount, 0, (size_t)nbuck * sizeof(int), stream);

  gemm_h_kernel<<<(n_nodes + 63) / 64, 256, 0, stream>>>(feat, W, h16, n_nodes);

  bhist_kernel<<<eb2, 256, 0, stream>>>(dst, bcount, n_edges, nbuck);
  bscan_kernel<<<1, 512, 0, stream>>>(bcount, bbase, bcursor, nbuck, n_edges);
  bscatter_kernel<<<eb2, 256, 0, stream>>>(src, dst, bcursor, tmpe, n_edges, nbuck);
  binB_kernel<<<nbuck, 256, 0, stream>>>(tmpe, bbase, edata, row_ptr, n_nodes, n_edges);

  agg_kernel<<<wb, 256, 0, stream>>>((const unsigned*)h16, row_ptr, edata,
                                     h_agg, n_nodes);

  // h16 dead -> reuse as t16; a16 written alongside
  unsigned short* t16 = h16;
  int n4 = n_nodes * OUT_FEATS / 4;
  tanh_kernel<<<(n4 + 255) / 256, 256, 0, stream>>>((const float4*)h_agg,
                                                    (ushort4*)t16, (ushort4*)a16, n4);

  softmax_kernel<<<wb, 256, 0, stream>>>((const unsigned*)a16, (const unsigned*)t16,
                                         row_ptr, edata, e_soft, n_nodes);
}